// Round 16
// baseline (49.941 us; speedup 1.0000x reference)
//
#include <hip/hip_runtime.h>
#include <hip/hip_bf16.h>

#define B_    64
#define DIM   640
#define TS    64
#define NT    10        // DIM/TS
#define NTP   55        // triu tile pairs
#define TRI   205120    // DIM*(DIM+1)/2
#define EPS   1e-5f
#define SQEPS 3.1622776601683794e-3f
#define KCH   16        // uint4 chunks per img row (256 B row stride)
#define TILE_U4 1024    // uint4 per 64-row tile image (16 KB)
#define TILE_B  16384

typedef __attribute__((ext_vector_type(8)))  short bf16x8;
typedef __attribute__((ext_vector_type(16))) float f32x16;

__device__ inline unsigned pk_bf16(float a, float b) {
    __hip_bfloat162 h = __float22bfloat162_rn(float2{a, b});
    return *reinterpret_cast<unsigned*>(&h);
}
// sum of squares of the two bf16 values packed in pk (as fp32)
__device__ inline float bsq(unsigned pk) {
    union { unsigned u; float f; } a, c;
    a.u = pk << 16;
    c.u = pk & 0xffff0000u;
    return a.f * a.f + c.f * c.f;
}
__device__ inline float fsq(float x) { return __builtin_amdgcn_sqrtf(x); }

__device__ inline void gload_lds16(const void* g, void* l) {
    __builtin_amdgcn_global_load_lds(
        (const __attribute__((address_space(1))) unsigned*)g,
        (__attribute__((address_space(3))) unsigned*)l, 16, 0, 0);
}
// stage one 16 KB tile: 4 waves x 4 segs x 64 lanes x 16 B (coalesced)
__device__ inline void stage_tile16(const char* __restrict__ gt, char* lt,
                                    int wv, int lane) {
    #pragma unroll
    for (int it = 0; it < 4; ++it) {
        const int seg = (wv * 4 + it) * 1024;
        gload_lds16(gt + seg + lane * 16, lt + seg);
    }
}

// ---------------------------------------------------------------------------
// K0 prep: per (b,s) convert 64x100 fp32 strip -> swizzled bf16 img tile
// (K zero-padded) + per-row sum of squares; zeroes its rowsum rows.
// ---------------------------------------------------------------------------
__global__ __launch_bounds__(256) void prep_kernel(
    const float* __restrict__ x, uint4* __restrict__ img,
    float* __restrict__ dsq, float* __restrict__ rowsum)
{
    const int blk = blockIdx.x;                 // b*NT + s
    const int b = blk / NT, s = blk % NT;
    const int t = threadIdx.x;
    const float4* src = (const float4*)x + (size_t)(b * DIM + s * TS) * 25;
    uint4* dst = img + (size_t)blk * TILE_U4;

    #pragma unroll
    for (int ff = 0; ff < 4; ++ff) {
        const int f = t + ff * 256;
        const int r = f >> 4, c = f & 15;
        uint4 p = {0u, 0u, 0u, 0u};
        float sq = 0.f;
        if (c <= 12) {
            float4 lo = src[(size_t)r * 25 + 2 * c];
            float4 hi = make_float4(0.f, 0.f, 0.f, 0.f);
            if (c < 12) hi = src[(size_t)r * 25 + 2 * c + 1];
            p.x = pk_bf16(lo.x, lo.y);
            p.y = pk_bf16(lo.z, lo.w);
            p.z = pk_bf16(hi.x, hi.y);
            p.w = pk_bf16(hi.z, hi.w);
            sq = bsq(p.x) + bsq(p.y) + bsq(p.z) + bsq(p.w);
        }
        dst[r * KCH + (c ^ (r & 15))] = p;
        sq += __shfl_xor(sq, 1);
        sq += __shfl_xor(sq, 2);
        sq += __shfl_xor(sq, 4);
        sq += __shfl_xor(sq, 8);
        if (c == 0) dsq[b * DIM + s * TS + r] = sq;
    }
    if (t < TS) rowsum[b * DIM + s * TS + t] = 0.f;
}

// ---------------------------------------------------------------------------
// K1 strip: ONE j-tile per block (6400 blocks), single-shot.  Partial dcov
// row sums for rows [s*64, s*64+64) over j-tile jt; 64 atomicAdds per block.
// ---------------------------------------------------------------------------
__global__ __launch_bounds__(256, 4) void strip_kernel(
    const uint4* __restrict__ img, const float* __restrict__ dsq,
    const float* __restrict__ temp, float* __restrict__ rowsum)
{
    __shared__ uint4 xj[TILE_U4];         // 16 KB
    __shared__ float dJs[TS];
    __shared__ float rpartw[2][TS];

    const int raw = blockIdx.x;                       // 6400 % 8 == 0
    const int bid = (raw & 7) * 800 + (raw >> 3);     // XCD-grouped
    const int b = bid / 100, rem = bid % 100;
    const int s = rem / 10, jt = rem % 10;
    const int t = threadIdx.x, wv = t >> 6, lane = t & 63;
    const int l31 = lane & 31, khalf = lane >> 5;
    const int iq = wv & 1, jq = wv >> 1;
    const float tts = expf(temp[0]);
    const char* base = (const char*)(img + (size_t)b * NT * TILE_U4);

    stage_tile16(base + (size_t)jt * TILE_B, (char*)xj, wv, lane);
    if (t < TS) dJs[t] = dsq[b * DIM + jt * TS + t];

    // own-strip A-fragments straight from global (L2-hot)
    const int irow = iq * 32 + l31;
    const uint4* own = img + (size_t)(b * NT + s) * TILE_U4;
    bf16x8 ifr[7];
    #pragma unroll
    for (int kk = 0; kk < 7; ++kk) {
        const int c = kk * 2 + khalf;
        ifr[kk] = *(const bf16x8*)&own[irow * KCH + (c ^ (irow & 15))];
    }
    const float dic = dsq[b * DIM + s * TS + irow];
    const int jr = jq * 32 + l31;
    __syncthreads();

    bf16x8 jfr[7];
    #pragma unroll
    for (int kk = 0; kk < 7; ++kk) {
        const int c = kk * 2 + khalf;
        jfr[kk] = *(const bf16x8*)&xj[jr * KCH + (c ^ (jr & 15))];
    }
    f32x16 acc = {};
    #pragma unroll
    for (int kk = 0; kk < 7; ++kk)
        acc = __builtin_amdgcn_mfma_f32_32x32x16_bf16(jfr[kk], ifr[kk],
                                                      acc, 0, 0, 0);
    const bool dg = (jt == s);
    float rsum = 0.f;
    #pragma unroll
    for (int r = 0; r < 16; ++r) {
        const int rf = (r & 3) + 8 * (r >> 2) + 4 * khalf;
        const int jrow = jq * 32 + rf;
        const float u = dJs[jrow] + dic - 2.f * acc[r];
        rsum += (dg && jrow == irow)
              ? SQEPS : fsq(tts * fmaxf(u, 0.f) + EPS);
    }
    rsum += __shfl_xor(rsum, 32);
    if (lane < 32) rpartw[jq][iq * 32 + lane] = rsum;
    __syncthreads();
    if (t < TS)
        atomicAdd(&rowsum[b * DIM + s * TS + t],
                  rpartw[0][t] + rpartw[1][t]);
}

// ---------------------------------------------------------------------------
// K1.5 means: per batch, e[k] = tm/2 - rowmean[k] (precomputed for K2).
// ---------------------------------------------------------------------------
__global__ __launch_bounds__(256) void means_kernel(
    const float* __restrict__ rowsum, float* __restrict__ e_g)
{
    __shared__ float red4[4];
    const int b = blockIdx.x, t = threadIdx.x;
    const int wv = t >> 6, lane = t & 63;
    const float* r0 = rowsum + b * DIM;

    const float v0 = r0[t];
    const float v1 = r0[t + 256];
    const float v2 = (t < 128) ? r0[t + 512] : 0.f;
    float ps = v0 + v1 + v2;
    ps += __shfl_xor(ps, 1);  ps += __shfl_xor(ps, 2);
    ps += __shfl_xor(ps, 4);  ps += __shfl_xor(ps, 8);
    ps += __shfl_xor(ps, 16); ps += __shfl_xor(ps, 32);
    if (lane == 0) red4[wv] = ps;
    __syncthreads();
    const float tm = (red4[0] + red4[1] + red4[2] + red4[3])
                   * (1.0f / ((float)DIM * (float)DIM));
    const float invD = 1.0f / (float)DIM;
    e_g[b * DIM + t]       = 0.5f * tm - v0 * invD;
    e_g[b * DIM + t + 256] = 0.5f * tm - v1 * invD;
    if (t < 128)
        e_g[b * DIM + t + 512] = 0.5f * tm - v2 * invD;
}

// XCD-grouped block id -> (b, ti, tj).  3520 % 8 == 0 -> bijective.
__device__ inline void decode_blk(int raw, int& b, int& ti, int& tj) {
    int bid = (raw & 7) * (B_ * NTP / 8) + (raw >> 3);
    b = bid / NTP;
    int tp = bid % NTP;
    int i = 0;
    while (tp >= NT - i) { tp -= NT - i; ++i; }
    ti = i; tj = i + tp;
}

// ---------------------------------------------------------------------------
// K2 write (r15-exact): ONE tile per block (3520 blocks), single-shot.
// ---------------------------------------------------------------------------
__global__ __launch_bounds__(256, 4) void write_kernel(
    const uint4* __restrict__ img, const float* __restrict__ dsq,
    const float* __restrict__ temp, const float* __restrict__ e_g,
    float* __restrict__ out)
{
    __shared__ uint4 xi[TILE_U4], xj2[TILE_U4];   // 32 KB
    __shared__ float dIs[TS], dJs[TS], eIs[TS], eJs[TS];

    int b, ti, tj; decode_blk(blockIdx.x, b, ti, tj);
    const int t = threadIdx.x, wv = t >> 6, lane = t & 63;
    const int l31 = lane & 31, khalf = lane >> 5;
    const int wm = wv >> 1, wn = wv & 1;
    const int i0 = ti * TS, j0 = tj * TS;
    const float tts = expf(temp[0]);
    const char* base = (const char*)(img + (size_t)b * NT * TILE_U4);

    stage_tile16(base + (size_t)ti * TILE_B, (char*)xi, wv, lane);
    if (ti != tj)   // block-uniform
        stage_tile16(base + (size_t)tj * TILE_B, (char*)xj2, wv, lane);

    if      (t < TS)     dIs[t]          = dsq[b * DIM + i0 + t];
    else if (t < 2 * TS) dJs[t - TS]     = dsq[b * DIM + j0 + (t - TS)];
    else if (t < 3 * TS) eIs[t - 2 * TS] = e_g[b * DIM + i0 + (t - 2 * TS)];
    else                 eJs[t - 3 * TS] = e_g[b * DIM + j0 + (t - 3 * TS)];
    __syncthreads();

    const uint4* xjp = (ti == tj) ? xi : xj2;
    const int arow = wm * 32 + l31;
    const int brow = wn * 32 + l31;

    bf16x8 afr[7], bfr7[7];
    #pragma unroll
    for (int kk = 0; kk < 7; ++kk) {
        const int c = kk * 2 + khalf;
        afr[kk]  = *(const bf16x8*)&xi[arow * KCH + (c ^ (arow & 15))];
        bfr7[kk] = *(const bf16x8*)&xjp[brow * KCH + (c ^ (brow & 15))];
    }
    f32x16 acc = {};
    #pragma unroll
    for (int kk = 0; kk < 7; ++kk)
        acc = __builtin_amdgcn_mfma_f32_32x32x16_bf16(afr[kk], bfr7[kk],
                                                      acc, 0, 0, 0);

    const int col_l = wn * 32 + l31;
    const int gj = j0 + col_l;
    const float djc = dJs[col_l], ejc = eJs[col_l];
    #pragma unroll
    for (int g = 0; g < 4; ++g) {
        const int rbase = wm * 32 + 8 * g + 4 * khalf;
        const float4 e4 = *(const float4*)&eIs[rbase];
        const float4 d4 = *(const float4*)&dIs[rbase];
        #pragma unroll
        for (int q = 0; q < 4; ++q) {
            const int r  = 4 * g + q;
            const int gi = i0 + rbase + q;
            float u = ((const float*)&d4)[q] + djc - 2.f * acc[r];
            float v = (gi == gj) ? SQEPS : fsq(tts * fmaxf(u, 0.f) + EPS);
            float cv = v + ((const float*)&e4)[q] + ejc;
            // branch-free symmetric store (diag tiles: mirrored lanes write
            // the same value to the same address -- benign)
            const unsigned lo = (unsigned)min(gi, gj);
            const unsigned hi2 = (unsigned)max(gi, gj);
            unsigned idx32 = (unsigned)b * TRI + lo * DIM
                           - ((lo * (lo - 1)) >> 1) - lo + hi2;
            out[idx32] = cv;
        }
    }
}

extern "C" void kernel_launch(void* const* d_in, const int* in_sizes, int n_in,
                              void* d_out, int out_size, void* d_ws, size_t ws_size,
                              hipStream_t stream)
{
    const float* x    = (const float*)d_in[0];
    const float* temp = (const float*)d_in[1];
    float* out         = (float*)d_out;

    float* rowsum      = (float*)d_ws;                    // [B_*DIM]
    float* dsq         = rowsum + B_ * DIM;               // [B_*DIM]
    float* e_g         = dsq + B_ * DIM;                  // [B_*DIM]
    uint4* img         = (uint4*)(e_g + B_ * DIM);        // 10.5 MB

    prep_kernel <<<B_ * NT,      256, 0, stream>>>(x, img, dsq, rowsum);
    strip_kernel<<<B_ * NT * NT, 256, 0, stream>>>(img, dsq, temp, rowsum);
    means_kernel<<<B_,           256, 0, stream>>>(rowsum, e_g);
    write_kernel<<<B_ * NTP,     256, 0, stream>>>(img, dsq, temp, e_g, out);
}

// Round 17
// 46.886 us; speedup vs baseline: 1.0652x; 1.0652x over previous
//
#include <hip/hip_runtime.h>
#include <hip/hip_bf16.h>

#define B_    64
#define DIM   640
#define TS    64
#define NT    10        // DIM/TS
#define NTP   55        // triu tile pairs
#define TRI   205120    // DIM*(DIM+1)/2
#define EPS   1e-5f
#define SQEPS 3.1622776601683794e-3f
#define KCH   16        // uint4 chunks per img row (256 B row stride)
#define TILE_U4 1024    // uint4 per 64-row tile image (16 KB)
#define TILE_B  16384

typedef __attribute__((ext_vector_type(8)))  short bf16x8;
typedef __attribute__((ext_vector_type(16))) float f32x16;

__device__ inline unsigned pk_bf16(float a, float b) {
    __hip_bfloat162 h = __float22bfloat162_rn(float2{a, b});
    return *reinterpret_cast<unsigned*>(&h);
}
// sum of squares of the two bf16 values packed in pk (as fp32)
__device__ inline float bsq(unsigned pk) {
    union { unsigned u; float f; } a, c;
    a.u = pk << 16;
    c.u = pk & 0xffff0000u;
    return a.f * a.f + c.f * c.f;
}
__device__ inline float fsq(float x) { return __builtin_amdgcn_sqrtf(x); }

__device__ inline void gload_lds16(const void* g, void* l) {
    __builtin_amdgcn_global_load_lds(
        (const __attribute__((address_space(1))) unsigned*)g,
        (__attribute__((address_space(3))) unsigned*)l, 16, 0, 0);
}
// stage one 16 KB tile: 4 waves x 4 segs x 64 lanes x 16 B (coalesced)
__device__ inline void stage_tile16(const char* __restrict__ gt, char* lt,
                                    int wv, int lane) {
    #pragma unroll
    for (int it = 0; it < 4; ++it) {
        const int seg = (wv * 4 + it) * 1024;
        gload_lds16(gt + seg + lane * 16, lt + seg);
    }
}

// ---------------------------------------------------------------------------
// K0 prep (r15-exact): per (b,s) convert 64x100 fp32 strip -> swizzled bf16
// img tile (K zero-padded) + per-row sum of squares, single pass over x.
// ---------------------------------------------------------------------------
__global__ __launch_bounds__(256) void prep_kernel(
    const float* __restrict__ x, uint4* __restrict__ img,
    float* __restrict__ dsq)
{
    const int blk = blockIdx.x;                 // b*NT + s
    const int b = blk / NT, s = blk % NT;
    const int t = threadIdx.x;
    const float4* src = (const float4*)x + (size_t)(b * DIM + s * TS) * 25;
    uint4* dst = img + (size_t)blk * TILE_U4;

    #pragma unroll
    for (int ff = 0; ff < 4; ++ff) {
        const int f = t + ff * 256;
        const int r = f >> 4, c = f & 15;
        uint4 p = {0u, 0u, 0u, 0u};
        float sq = 0.f;
        if (c <= 12) {
            float4 lo = src[(size_t)r * 25 + 2 * c];
            float4 hi = make_float4(0.f, 0.f, 0.f, 0.f);
            if (c < 12) hi = src[(size_t)r * 25 + 2 * c + 1];
            p.x = pk_bf16(lo.x, lo.y);
            p.y = pk_bf16(lo.z, lo.w);
            p.z = pk_bf16(hi.x, hi.y);
            p.w = pk_bf16(hi.z, hi.w);
            sq = bsq(p.x) + bsq(p.y) + bsq(p.z) + bsq(p.w);
        }
        dst[r * KCH + (c ^ (r & 15))] = p;
        sq += __shfl_xor(sq, 1);
        sq += __shfl_xor(sq, 2);
        sq += __shfl_xor(sq, 4);
        sq += __shfl_xor(sq, 8);
        if (c == 0) dsq[b * DIM + s * TS + r] = sq;
    }
}

// ---------------------------------------------------------------------------
// K1 strip (r15-exact): one block per (b, strip s, j-parity h).
// ---------------------------------------------------------------------------
__global__ __launch_bounds__(256, 4) void strip_kernel(
    const uint4* __restrict__ img, const float* __restrict__ dsq,
    const float* __restrict__ temp, float* __restrict__ rowsum_part)
{
    __shared__ uint4 xj[2][TILE_U4];      // 32 KB
    __shared__ float dAll[DIM];
    __shared__ float rpartw[2][TS];

    const int raw = blockIdx.x;                       // 1280 % 8 == 0
    const int bid = (raw & 7) * 160 + (raw >> 3);     // XCD-grouped
    const int b = bid / 20, rem = bid % 20;
    const int s = rem >> 1, h = rem & 1;
    const int t = threadIdx.x, wv = t >> 6, lane = t & 63;
    const int l31 = lane & 31, khalf = lane >> 5;
    const int iq = wv & 1, jq = wv >> 1;
    const float tts = expf(temp[0]);
    const char* base = (const char*)(img + (size_t)b * NT * TILE_U4);

    stage_tile16(base + (size_t)h * TILE_B, (char*)xj[0], wv, lane);
    for (int k = t; k < DIM; k += 256) dAll[k] = dsq[b * DIM + k];

    const int irow = iq * 32 + l31;
    const uint4* own = img + (size_t)(b * NT + s) * TILE_U4;
    bf16x8 ifr[7];
    #pragma unroll
    for (int kk = 0; kk < 7; ++kk) {
        const int c = kk * 2 + khalf;
        ifr[kk] = *(const bf16x8*)&own[irow * KCH + (c ^ (irow & 15))];
    }
    const int jr = jq * 32 + l31;
    __syncthreads();
    const float dic = dAll[s * TS + irow];

    float rsum = 0.f;
    #pragma unroll
    for (int jj = 0; jj < 5; ++jj) {
        const int jt = h + 2 * jj;
        if (jj < 4)
            stage_tile16(base + (size_t)(jt + 2) * TILE_B,
                         (char*)xj[(jj + 1) & 1], wv, lane);
        const uint4* buf = xj[jj & 1];
        bf16x8 jfr[7];
        #pragma unroll
        for (int kk = 0; kk < 7; ++kk) {
            const int c = kk * 2 + khalf;
            jfr[kk] = *(const bf16x8*)&buf[jr * KCH + (c ^ (jr & 15))];
        }
        f32x16 acc = {};
        #pragma unroll
        for (int kk = 0; kk < 7; ++kk)
            acc = __builtin_amdgcn_mfma_f32_32x32x16_bf16(jfr[kk], ifr[kk],
                                                          acc, 0, 0, 0);
        const bool dg = (jt == s);
        #pragma unroll
        for (int r = 0; r < 16; ++r) {
            const int rf = (r & 3) + 8 * (r >> 2) + 4 * khalf;
            const int jrow = jq * 32 + rf;
            const float dj = dAll[jt * TS + jrow];
            float u = dj + dic - 2.f * acc[r];
            rsum += (dg && jrow == irow)
                  ? SQEPS : fsq(tts * fmaxf(u, 0.f) + EPS);
        }
        __syncthreads();   // buffer consumed; next stage complete
    }

    rsum += __shfl_xor(rsum, 32);
    if (lane < 32) rpartw[jq][iq * 32 + lane] = rsum;
    __syncthreads();
    if (t < TS)
        rowsum_part[h * (B_ * DIM) + b * DIM + s * TS + t]
            = rpartw[0][t] + rpartw[1][t];
}

// ---------------------------------------------------------------------------
// K1.5 means (r15-exact): per batch, e[k] = tm/2 - rowmean[k].
// ---------------------------------------------------------------------------
__global__ __launch_bounds__(256) void means_kernel(
    const float* __restrict__ rowsum_part, float* __restrict__ e_g)
{
    __shared__ float red4[4];
    const int b = blockIdx.x, t = threadIdx.x;
    const int wv = t >> 6, lane = t & 63;
    const float* r0 = rowsum_part + b * DIM;
    const float* r1 = rowsum_part + (B_ * DIM) + b * DIM;

    const float v0 = r0[t] + r1[t];
    const float v1 = r0[t + 256] + r1[t + 256];
    const float v2 = (t < 128) ? (r0[t + 512] + r1[t + 512]) : 0.f;
    float ps = v0 + v1 + v2;
    ps += __shfl_xor(ps, 1);  ps += __shfl_xor(ps, 2);
    ps += __shfl_xor(ps, 4);  ps += __shfl_xor(ps, 8);
    ps += __shfl_xor(ps, 16); ps += __shfl_xor(ps, 32);
    if (lane == 0) red4[wv] = ps;
    __syncthreads();
    const float tm = (red4[0] + red4[1] + red4[2] + red4[3])
                   * (1.0f / ((float)DIM * (float)DIM));
    const float invD = 1.0f / (float)DIM;
    e_g[b * DIM + t]       = 0.5f * tm - v0 * invD;
    e_g[b * DIM + t + 256] = 0.5f * tm - v1 * invD;
    if (t < 128)
        e_g[b * DIM + t + 512] = 0.5f * tm - v2 * invD;
}

// XCD-grouped block id -> (b, ti, tj).  3520 % 8 == 0 -> bijective.
__device__ inline void decode_blk(int raw, int& b, int& ti, int& tj) {
    int bid = (raw & 7) * (B_ * NTP / 8) + (raw >> 3);
    b = bid / NTP;
    int tp = bid % NTP;
    int i = 0;
    while (tp >= NT - i) { tp -= NT - i; ++i; }
    ti = i; tj = i + tp;
}

// ---------------------------------------------------------------------------
// K2 write: ONE tile per block (3520 blocks), single-shot.  A-frags direct
// from L2-resident img (r10-proven); B-tile LDS-staged (coalesced).  Diag
// tiles reuse the A-frags (no stage at all).  LDS 17 KB.
// ---------------------------------------------------------------------------
__global__ __launch_bounds__(256, 4) void write_kernel(
    const uint4* __restrict__ img, const float* __restrict__ dsq,
    const float* __restrict__ temp, const float* __restrict__ e_g,
    float* __restrict__ out)
{
    __shared__ uint4 xj2[TILE_U4];                // 16 KB
    __shared__ float dIs[TS], dJs[TS], eIs[TS], eJs[TS];

    int b, ti, tj; decode_blk(blockIdx.x, b, ti, tj);
    const int t = threadIdx.x, wv = t >> 6, lane = t & 63;
    const int l31 = lane & 31, khalf = lane >> 5;
    const int wm = wv >> 1, wn = wv & 1;
    const int i0 = ti * TS, j0 = tj * TS;
    const float tts = expf(temp[0]);
    const char* base = (const char*)(img + (size_t)b * NT * TILE_U4);
    const bool dg = (ti == tj);

    if (!dg)   // block-uniform
        stage_tile16(base + (size_t)tj * TILE_B, (char*)xj2, wv, lane);

    // A-fragments straight from global (L2-hot), overlapping the stage
    const int arow = wm * 32 + l31;
    const uint4* ownt = img + (size_t)(b * NT + ti) * TILE_U4;
    bf16x8 afr[7];
    #pragma unroll
    for (int kk = 0; kk < 7; ++kk) {
        const int c = kk * 2 + khalf;
        afr[kk] = *(const bf16x8*)&ownt[arow * KCH + (c ^ (arow & 15))];
    }

    if      (t < TS)     dIs[t]          = dsq[b * DIM + i0 + t];
    else if (t < 2 * TS) dJs[t - TS]     = dsq[b * DIM + j0 + (t - TS)];
    else if (t < 3 * TS) eIs[t - 2 * TS] = e_g[b * DIM + i0 + (t - 2 * TS)];
    else                 eJs[t - 3 * TS] = e_g[b * DIM + j0 + (t - 3 * TS)];
    __syncthreads();

    const int brow = wn * 32 + l31;
    bf16x8 bfr7[7];
    if (!dg) {
        #pragma unroll
        for (int kk = 0; kk < 7; ++kk) {
            const int c = kk * 2 + khalf;
            bfr7[kk] = *(const bf16x8*)&xj2[brow * KCH + (c ^ (brow & 15))];
        }
    } else {
        // diag tile: B-frags direct from global too (same tile as A)
        #pragma unroll
        for (int kk = 0; kk < 7; ++kk) {
            const int c = kk * 2 + khalf;
            bfr7[kk] = *(const bf16x8*)&ownt[brow * KCH + (c ^ (brow & 15))];
        }
    }

    f32x16 acc = {};
    #pragma unroll
    for (int kk = 0; kk < 7; ++kk)
        acc = __builtin_amdgcn_mfma_f32_32x32x16_bf16(afr[kk], bfr7[kk],
                                                      acc, 0, 0, 0);

    const int col_l = wn * 32 + l31;
    const int gj = j0 + col_l;
    const float djc = dJs[col_l], ejc = eJs[col_l];
    #pragma unroll
    for (int g = 0; g < 4; ++g) {
        const int rbase = wm * 32 + 8 * g + 4 * khalf;
        const float4 e4 = *(const float4*)&eIs[rbase];
        const float4 d4 = *(const float4*)&dIs[rbase];
        #pragma unroll
        for (int q = 0; q < 4; ++q) {
            const int r  = 4 * g + q;
            const int gi = i0 + rbase + q;
            float u = ((const float*)&d4)[q] + djc - 2.f * acc[r];
            float v = (gi == gj) ? SQEPS : fsq(tts * fmaxf(u, 0.f) + EPS);
            float cv = v + ((const float*)&e4)[q] + ejc;
            // branch-free symmetric store (diag tiles: mirrored lanes write
            // the same value to the same address -- benign)
            const unsigned lo = (unsigned)min(gi, gj);
            const unsigned hi2 = (unsigned)max(gi, gj);
            unsigned idx32 = (unsigned)b * TRI + lo * DIM
                           - ((lo * (lo - 1)) >> 1) - lo + hi2;
            out[idx32] = cv;
        }
    }
}

extern "C" void kernel_launch(void* const* d_in, const int* in_sizes, int n_in,
                              void* d_out, int out_size, void* d_ws, size_t ws_size,
                              hipStream_t stream)
{
    const float* x    = (const float*)d_in[0];
    const float* temp = (const float*)d_in[1];
    float* out         = (float*)d_out;

    float* rowsum_part = (float*)d_ws;                    // [2][B_*DIM]
    float* dsq         = rowsum_part + 2 * B_ * DIM;      // [B_*DIM]
    float* e_g         = dsq + B_ * DIM;                  // [B_*DIM]
    uint4* img         = (uint4*)(e_g + B_ * DIM);        // 10.5 MB

    prep_kernel <<<B_ * NT,     256, 0, stream>>>(x, img, dsq);
    strip_kernel<<<2 * B_ * NT, 256, 0, stream>>>(img, dsq, temp, rowsum_part);
    means_kernel<<<B_,          256, 0, stream>>>(rowsum_part, e_g);
    write_kernel<<<B_ * NTP,    256, 0, stream>>>(img, dsq, temp, e_g, out);
}

// Round 18
// 45.911 us; speedup vs baseline: 1.0878x; 1.0212x over previous
//
#include <hip/hip_runtime.h>
#include <hip/hip_bf16.h>

#define B_    64
#define DIM   640
#define TS    64
#define NT    10        // DIM/TS
#define NTP   55        // triu tile pairs
#define TRI   205120    // DIM*(DIM+1)/2
#define EPS   1e-5f
#define SQEPS 3.1622776601683794e-3f
#define KCH   16        // uint4 chunks per img row (256 B row stride)
#define TILE_U4 1024    // uint4 per 64-row tile image (16 KB)
#define TILE_B  16384

typedef __attribute__((ext_vector_type(8)))  short bf16x8;
typedef __attribute__((ext_vector_type(16))) float f32x16;

__device__ inline unsigned pk_bf16(float a, float b) {
    __hip_bfloat162 h = __float22bfloat162_rn(float2{a, b});
    return *reinterpret_cast<unsigned*>(&h);
}
// sum of squares of the two bf16 values packed in pk (as fp32)
__device__ inline float bsq(unsigned pk) {
    union { unsigned u; float f; } a, c;
    a.u = pk << 16;
    c.u = pk & 0xffff0000u;
    return a.f * a.f + c.f * c.f;
}
__device__ inline float fsq(float x) { return __builtin_amdgcn_sqrtf(x); }

__device__ inline void gload_lds16(const void* g, void* l) {
    __builtin_amdgcn_global_load_lds(
        (const __attribute__((address_space(1))) unsigned*)g,
        (__attribute__((address_space(3))) unsigned*)l, 16, 0, 0);
}
// stage one 16 KB tile: 4 waves x 4 segs x 64 lanes x 16 B (coalesced)
__device__ inline void stage_tile16(const char* __restrict__ gt, char* lt,
                                    int wv, int lane) {
    #pragma unroll
    for (int it = 0; it < 4; ++it) {
        const int seg = (wv * 4 + it) * 1024;
        gload_lds16(gt + seg + lane * 16, lt + seg);
    }
}

// ---------------------------------------------------------------------------
// K0 prep: per (b,s) convert 64x100 fp32 strip -> swizzled bf16 img tile
// (K zero-padded) + per-row sum of squares, single pass over x.
// ---------------------------------------------------------------------------
__global__ __launch_bounds__(256) void prep_kernel(
    const float* __restrict__ x, uint4* __restrict__ img,
    float* __restrict__ dsq)
{
    const int blk = blockIdx.x;                 // b*NT + s
    const int b = blk / NT, s = blk % NT;
    const int t = threadIdx.x;
    const float4* src = (const float4*)x + (size_t)(b * DIM + s * TS) * 25;
    uint4* dst = img + (size_t)blk * TILE_U4;

    #pragma unroll
    for (int ff = 0; ff < 4; ++ff) {
        const int f = t + ff * 256;
        const int r = f >> 4, c = f & 15;
        uint4 p = {0u, 0u, 0u, 0u};
        float sq = 0.f;
        if (c <= 12) {
            float4 lo = src[(size_t)r * 25 + 2 * c];
            float4 hi = make_float4(0.f, 0.f, 0.f, 0.f);
            if (c < 12) hi = src[(size_t)r * 25 + 2 * c + 1];
            p.x = pk_bf16(lo.x, lo.y);
            p.y = pk_bf16(lo.z, lo.w);
            p.z = pk_bf16(hi.x, hi.y);
            p.w = pk_bf16(hi.z, hi.w);
            sq = bsq(p.x) + bsq(p.y) + bsq(p.z) + bsq(p.w);
        }
        dst[r * KCH + (c ^ (r & 15))] = p;
        sq += __shfl_xor(sq, 1);
        sq += __shfl_xor(sq, 2);
        sq += __shfl_xor(sq, 4);
        sq += __shfl_xor(sq, 8);
        if (c == 0) dsq[b * DIM + s * TS + r] = sq;
    }
}

// ---------------------------------------------------------------------------
// K1 strip: one block per (b, strip s, j-parity h).  Partial dcov row sums
// for rows [s*64, s*64+64) over j-tiles of parity h.  A-frags direct from L2;
// j-tiles double-buffered via global_load_lds.
// ---------------------------------------------------------------------------
__global__ __launch_bounds__(256, 4) void strip_kernel(
    const uint4* __restrict__ img, const float* __restrict__ dsq,
    const float* __restrict__ temp, float* __restrict__ rowsum_part)
{
    __shared__ uint4 xj[2][TILE_U4];      // 32 KB
    __shared__ float dAll[DIM];
    __shared__ float rpartw[2][TS];

    const int raw = blockIdx.x;                       // 1280 % 8 == 0
    const int bid = (raw & 7) * 160 + (raw >> 3);     // XCD-grouped
    const int b = bid / 20, rem = bid % 20;
    const int s = rem >> 1, h = rem & 1;
    const int t = threadIdx.x, wv = t >> 6, lane = t & 63;
    const int l31 = lane & 31, khalf = lane >> 5;
    const int iq = wv & 1, jq = wv >> 1;
    const float tts = expf(temp[0]);
    const char* base = (const char*)(img + (size_t)b * NT * TILE_U4);

    stage_tile16(base + (size_t)h * TILE_B, (char*)xj[0], wv, lane);
    for (int k = t; k < DIM; k += 256) dAll[k] = dsq[b * DIM + k];

    const int irow = iq * 32 + l31;
    const uint4* own = img + (size_t)(b * NT + s) * TILE_U4;
    bf16x8 ifr[7];
    #pragma unroll
    for (int kk = 0; kk < 7; ++kk) {
        const int c = kk * 2 + khalf;
        ifr[kk] = *(const bf16x8*)&own[irow * KCH + (c ^ (irow & 15))];
    }
    const int jr = jq * 32 + l31;
    __syncthreads();
    const float dic = dAll[s * TS + irow];

    float rsum = 0.f;
    #pragma unroll
    for (int jj = 0; jj < 5; ++jj) {
        const int jt = h + 2 * jj;
        if (jj < 4)
            stage_tile16(base + (size_t)(jt + 2) * TILE_B,
                         (char*)xj[(jj + 1) & 1], wv, lane);
        const uint4* buf = xj[jj & 1];
        bf16x8 jfr[7];
        #pragma unroll
        for (int kk = 0; kk < 7; ++kk) {
            const int c = kk * 2 + khalf;
            jfr[kk] = *(const bf16x8*)&buf[jr * KCH + (c ^ (jr & 15))];
        }
        f32x16 acc = {};
        #pragma unroll
        for (int kk = 0; kk < 7; ++kk)
            acc = __builtin_amdgcn_mfma_f32_32x32x16_bf16(jfr[kk], ifr[kk],
                                                          acc, 0, 0, 0);
        const bool dg = (jt == s);
        #pragma unroll
        for (int r = 0; r < 16; ++r) {
            const int rf = (r & 3) + 8 * (r >> 2) + 4 * khalf;
            const int jrow = jq * 32 + rf;
            const float dj = dAll[jt * TS + jrow];
            float u = dj + dic - 2.f * acc[r];
            rsum += (dg && jrow == irow)
                  ? SQEPS : fsq(tts * fmaxf(u, 0.f) + EPS);
        }
        __syncthreads();   // buffer consumed; next stage complete
    }

    rsum += __shfl_xor(rsum, 32);
    if (lane < 32) rpartw[jq][iq * 32 + lane] = rsum;
    __syncthreads();
    if (t < TS)
        rowsum_part[h * (B_ * DIM) + b * DIM + s * TS + t]
            = rpartw[0][t] + rpartw[1][t];
}

// ---------------------------------------------------------------------------
// K1.5 means: per batch, e[k] = tm/2 - rowmean[k] (precomputed for K2).
// ---------------------------------------------------------------------------
__global__ __launch_bounds__(256) void means_kernel(
    const float* __restrict__ rowsum_part, float* __restrict__ e_g)
{
    __shared__ float red4[4];
    const int b = blockIdx.x, t = threadIdx.x;
    const int wv = t >> 6, lane = t & 63;
    const float* r0 = rowsum_part + b * DIM;
    const float* r1 = rowsum_part + (B_ * DIM) + b * DIM;

    const float v0 = r0[t] + r1[t];
    const float v1 = r0[t + 256] + r1[t + 256];
    const float v2 = (t < 128) ? (r0[t + 512] + r1[t + 512]) : 0.f;
    float ps = v0 + v1 + v2;
    ps += __shfl_xor(ps, 1);  ps += __shfl_xor(ps, 2);
    ps += __shfl_xor(ps, 4);  ps += __shfl_xor(ps, 8);
    ps += __shfl_xor(ps, 16); ps += __shfl_xor(ps, 32);
    if (lane == 0) red4[wv] = ps;
    __syncthreads();
    const float tm = (red4[0] + red4[1] + red4[2] + red4[3])
                   * (1.0f / ((float)DIM * (float)DIM));
    const float invD = 1.0f / (float)DIM;
    e_g[b * DIM + t]       = 0.5f * tm - v0 * invD;
    e_g[b * DIM + t + 256] = 0.5f * tm - v1 * invD;
    if (t < 128)
        e_g[b * DIM + t + 512] = 0.5f * tm - v2 * invD;
}

// XCD-grouped block id -> (b, ti, tj).  3520 % 8 == 0 -> bijective.
__device__ inline void decode_blk(int raw, int& b, int& ti, int& tj) {
    int bid = (raw & 7) * (B_ * NTP / 8) + (raw >> 3);
    b = bid / NTP;
    int tp = bid % NTP;
    int i = 0;
    while (tp >= NT - i) { tp -= NT - i; ++i; }
    ti = i; tj = i + tp;
}

// ---------------------------------------------------------------------------
// K2 write: ONE tile per block (3520 blocks), single-shot, one barrier.
// Stage tile-i/tile-j via global_load_lds, centering params precomputed,
// 7 MFMAs, branch-free symmetric packed-triu stores.
// ---------------------------------------------------------------------------
__global__ __launch_bounds__(256, 4) void write_kernel(
    const uint4* __restrict__ img, const float* __restrict__ dsq,
    const float* __restrict__ temp, const float* __restrict__ e_g,
    float* __restrict__ out)
{
    __shared__ uint4 xi[TILE_U4], xj2[TILE_U4];   // 32 KB
    __shared__ float dIs[TS], dJs[TS], eIs[TS], eJs[TS];

    int b, ti, tj; decode_blk(blockIdx.x, b, ti, tj);
    const int t = threadIdx.x, wv = t >> 6, lane = t & 63;
    const int l31 = lane & 31, khalf = lane >> 5;
    const int wm = wv >> 1, wn = wv & 1;
    const int i0 = ti * TS, j0 = tj * TS;
    const float tts = expf(temp[0]);
    const char* base = (const char*)(img + (size_t)b * NT * TILE_U4);

    stage_tile16(base + (size_t)ti * TILE_B, (char*)xi, wv, lane);
    if (ti != tj)   // block-uniform
        stage_tile16(base + (size_t)tj * TILE_B, (char*)xj2, wv, lane);

    if      (t < TS)     dIs[t]          = dsq[b * DIM + i0 + t];
    else if (t < 2 * TS) dJs[t - TS]     = dsq[b * DIM + j0 + (t - TS)];
    else if (t < 3 * TS) eIs[t - 2 * TS] = e_g[b * DIM + i0 + (t - 2 * TS)];
    else                 eJs[t - 3 * TS] = e_g[b * DIM + j0 + (t - 3 * TS)];
    __syncthreads();

    const uint4* xjp = (ti == tj) ? xi : xj2;
    const int arow = wm * 32 + l31;
    const int brow = wn * 32 + l31;

    bf16x8 afr[7], bfr7[7];
    #pragma unroll
    for (int kk = 0; kk < 7; ++kk) {
        const int c = kk * 2 + khalf;
        afr[kk]  = *(const bf16x8*)&xi[arow * KCH + (c ^ (arow & 15))];
        bfr7[kk] = *(const bf16x8*)&xjp[brow * KCH + (c ^ (brow & 15))];
    }
    f32x16 acc = {};
    #pragma unroll
    for (int kk = 0; kk < 7; ++kk)
        acc = __builtin_amdgcn_mfma_f32_32x32x16_bf16(afr[kk], bfr7[kk],
                                                      acc, 0, 0, 0);

    const int col_l = wn * 32 + l31;
    const int gj = j0 + col_l;
    const float djc = dJs[col_l], ejc = eJs[col_l];
    #pragma unroll
    for (int g = 0; g < 4; ++g) {
        const int rbase = wm * 32 + 8 * g + 4 * khalf;
        const float4 e4 = *(const float4*)&eIs[rbase];
        const float4 d4 = *(const float4*)&dIs[rbase];
        #pragma unroll
        for (int q = 0; q < 4; ++q) {
            const int r  = 4 * g + q;
            const int gi = i0 + rbase + q;
            float u = ((const float*)&d4)[q] + djc - 2.f * acc[r];
            float v = (gi == gj) ? SQEPS : fsq(tts * fmaxf(u, 0.f) + EPS);
            float cv = v + ((const float*)&e4)[q] + ejc;
            // branch-free symmetric store (diag tiles: mirrored lanes write
            // the same value to the same address -- benign)
            const unsigned lo = (unsigned)min(gi, gj);
            const unsigned hi2 = (unsigned)max(gi, gj);
            unsigned idx32 = (unsigned)b * TRI + lo * DIM
                           - ((lo * (lo - 1)) >> 1) - lo + hi2;
            out[idx32] = cv;
        }
    }
}

extern "C" void kernel_launch(void* const* d_in, const int* in_sizes, int n_in,
                              void* d_out, int out_size, void* d_ws, size_t ws_size,
                              hipStream_t stream)
{
    const float* x    = (const float*)d_in[0];
    const float* temp = (const float*)d_in[1];
    float* out         = (float*)d_out;

    float* rowsum_part = (float*)d_ws;                    // [2][B_*DIM]
    float* dsq         = rowsum_part + 2 * B_ * DIM;      // [B_*DIM]
    float* e_g         = dsq + B_ * DIM;                  // [B_*DIM]
    uint4* img         = (uint4*)(e_g + B_ * DIM);        // 10.5 MB

    prep_kernel <<<B_ * NT,     256, 0, stream>>>(x, img, dsq);
    strip_kernel<<<2 * B_ * NT, 256, 0, stream>>>(img, dsq, temp, rowsum_part);
    means_kernel<<<B_,          256, 0, stream>>>(rowsum_part, e_g);
    write_kernel<<<B_ * NTP,    256, 0, stream>>>(img, dsq, temp, e_g, out);
}